// Round 7
// baseline (409.969 us; speedup 1.0000x reference)
//
#include <hip/hip_runtime.h>

#define EPSQ 1e-8f
#define QBC  127.0f
#define LNE  1e-5f

typedef float f32x4 __attribute__((ext_vector_type(4)));

// ---- sdot4: int8x4 dot product ----
#if defined(__has_builtin)
#  if __has_builtin(__builtin_amdgcn_sdot4)
#    define SDOT4(a,b,c) __builtin_amdgcn_sdot4((a),(b),(c),false)
#  endif
#endif
#ifndef SDOT4
__device__ __forceinline__ int sdot4_sw(int a, int b, int c){
  c += ((a<<24)>>24) * ((b<<24)>>24);
  c += ((a<<16)>>24) * ((b<<16)>>24);
  c += ((a<< 8)>>24) * ((b<< 8)>>24);
  c += ( a>>24     ) * ( b>>24     );
  return c;
}
#  define SDOT4(a,b,c) sdot4_sw((a),(b),(c))
#endif

// ws byte offsets
constexpr size_t OFF_WPK  = 0;                       // 5*1024 ints (packed ternary rows)
constexpr size_t OFF_BETA = 20480;                   // 5 floats (pad)
constexpr size_t OFF_IG   = 20544;                   // 131072 floats: amax/127 per row
constexpr size_t OFF_MR   = OFF_IG + 524288;         // 131072 float2: (mean, rsqrt) per row
constexpr size_t OFF_Q    = OFF_MR + 1048576;        // 8388608 shorts
constexpr size_t OFF_K    = OFF_Q  + 16777216;
constexpr size_t OFF_V    = OFF_K  + 16777216;
constexpr size_t OFF_SC   = OFF_V  + 16777216;       // 131072 floats (scores)

__device__ __forceinline__ float gelu_f(float v){
  return 0.5f * v * (1.0f + erff(v * 0.70710678118654752f));
}
__device__ __forceinline__ int pack4(float q0, float q1, float q2, float q3){
  return ((int)q0 & 255) | (((int)q1 & 255) << 8) | (((int)q2 & 255) << 16) | (((int)q3 & 255) << 24);
}

// ---------------- K1: blocks 0-4 weight quantize+pack; blocks 5-36 conv path ------------------
__global__ __launch_bounds__(1024) void k_prep(
    const float* qw, const float* kw, const float* vw, const float* f1w, const float* f2w,
    const float* it2, const float* c1w, const float* c1b, const float* c2w, const float* c2b,
    const float* c3w, const float* c3b, int* __restrict__ wpk, float* __restrict__ beta5,
    float* __restrict__ sco){
  __shared__ float smem[1024 + 2*64*65];
  int t = threadIdx.x;
  if (blockIdx.x < 5){
    int m = blockIdx.x;
    const float* w = (m==0)?qw:(m==1)?kw:(m==2)?vw:(m==3)?f1w:f2w;
    float* red = smem;
    float s = 0.f;
    for (int i = t; i < 4096; i += 1024) s += fabsf(w[i]);
    red[t] = s; __syncthreads();
    for (int o = 512; o > 0; o >>= 1){ if (t < o) red[t] += red[t+o]; __syncthreads(); }
    float beta = fmaxf(red[0] * (1.0f/4096.0f), EPSQ);
    if (t == 0) beta5[m] = beta;
    int* dst = wpk + m*1024;
    if (t < 1024){
      int row = t >> 4, kp = t & 15;
      int v = 0;
      #pragma unroll
      for (int j = 0; j < 4; j++){
        float q = rintf(w[row*64 + kp*4 + j] / beta);
        q = fminf(fmaxf(q, -1.f), 1.f);
        v |= ((int)q & 255) << (8*j);
      }
      dst[t] = v;
    }
  } else {
    int b = blockIdx.x - 5;
    float* in32 = smem;
    float (*Aa)[65] = (float(*)[65])(smem + 1024);
    float (*Bb)[65] = (float(*)[65])(smem + 1024 + 64*65);
    for (int i = t; i < 1024; i += 1024) in32[i] = it2[b*1024 + i];
    __syncthreads();
    for (int p = t; p < 4096; p += 1024){
      int i = p >> 6, j = p & 63;
      float si = 0.5f*i - 0.25f, fi = floorf(si), wi = si - fi;
      int i0 = min(max((int)fi, 0), 31), i1 = min(max((int)fi + 1, 0), 31);
      float sj = 0.5f*j - 0.25f, fj = floorf(sj), wj = sj - fj;
      int j0 = min(max((int)fj, 0), 31), j1 = min(max((int)fj + 1, 0), 31);
      float v00 = in32[i0*32+j0], v01 = in32[i0*32+j1];
      float v10 = in32[i1*32+j0], v11 = in32[i1*32+j1];
      Aa[i][j] = (1.f-wi)*((1.f-wj)*v00 + wj*v01) + wi*((1.f-wj)*v10 + wj*v11);
    }
    __syncthreads();
    {
      float w9[9]; for (int q2=0;q2<9;q2++) w9[q2]=c1w[q2]; float bb = c1b[0];
      for (int p = t; p < 4096; p += 1024){
        int i = p>>6, j = p&63; float s = bb;
        #pragma unroll
        for (int di=-1; di<=1; di++)
          #pragma unroll
          for (int dj=-1; dj<=1; dj++){
            int ii=i+di, jj=j+dj;
            if (ii>=0 && ii<64 && jj>=0 && jj<64) s += w9[(di+1)*3+dj+1]*Aa[ii][jj];
          }
        Bb[i][j] = gelu_f(s);
      }
    }
    __syncthreads();
    {
      float w9[9]; for (int q2=0;q2<9;q2++) w9[q2]=c2w[q2]; float bb = c2b[0];
      for (int p = t; p < 4096; p += 1024){
        int i = p>>6, j = p&63; float s = bb;
        #pragma unroll
        for (int di=-1; di<=1; di++)
          #pragma unroll
          for (int dj=-1; dj<=1; dj++){
            int ii=i+di, jj=j+dj;
            if (ii>=0 && ii<64 && jj>=0 && jj<64) s += w9[(di+1)*3+dj+1]*Bb[ii][jj];
          }
        Aa[i][j] = gelu_f(s);
      }
    }
    __syncthreads();
    {
      float w9[9]; for (int q2=0;q2<9;q2++) w9[q2]=c3w[q2]; float bb = c3b[0];
      for (int p = t; p < 4096; p += 1024){
        int i = p>>6, j = p&63; float s = bb;
        #pragma unroll
        for (int di=-1; di<=1; di++)
          #pragma unroll
          for (int dj=-1; dj<=1; dj++){
            int ii=i+di, jj=j+dj;
            if (ii>=0 && ii<64 && jj>=0 && jj<64) s += w9[(di+1)*3+dj+1]*Aa[ii][jj];
          }
        sco[b*4096 + p] = gelu_f(s);
      }
    }
  }
}

// ---------------- K2: LN1 + quant + QKV int8 GEMM -> int16 accums ------------------------------
__global__ __launch_bounds__(256,8) void k_qkv(const float* __restrict__ x,
    const float* __restrict__ ln1g, const float* __restrict__ ln1b,
    const int* __restrict__ wpk, float2* __restrict__ mr, float* __restrict__ ig,
    short* __restrict__ q16, short* __restrict__ k16, short* __restrict__ v16){
  __shared__ int Wp[3][64][17];
  __shared__ int Xp[64][17];
  int t = threadIdx.x;
  for (int i = t; i < 3072; i += 256){
    int m = i >> 10, rem = i & 1023;
    Wp[m][rem>>4][rem&15] = wpk[i];
  }
  int c = t >> 2, g = t & 3;
  long n = (long)blockIdx.x * 64 + c;
  const float* xr = x + n*64 + g*16;
  float xv[16];
  #pragma unroll
  for (int i4 = 0; i4 < 4; i4++){
    float4 f = ((const float4*)xr)[i4];
    xv[4*i4+0]=f.x; xv[4*i4+1]=f.y; xv[4*i4+2]=f.z; xv[4*i4+3]=f.w;
  }
  float s = 0.f;
  #pragma unroll
  for (int i = 0; i < 16; i++) s += xv[i];
  s += __shfl_xor(s,1); s += __shfl_xor(s,2);
  float mean = s * (1.0f/64.0f);
  float vs = 0.f;
  #pragma unroll
  for (int i = 0; i < 16; i++){ float dd = xv[i]-mean; vs += dd*dd; }
  vs += __shfl_xor(vs,1); vs += __shfl_xor(vs,2);
  float rs = rsqrtf(vs*(1.0f/64.0f) + LNE);
  float xnv[16]; float amax = 0.f;
  #pragma unroll
  for (int i = 0; i < 16; i++){
    float u = (xv[i]-mean)*rs*ln1g[g*16+i] + ln1b[g*16+i];
    xnv[i] = u; amax = fmaxf(amax, fabsf(u));
  }
  amax = fmaxf(amax, __shfl_xor(amax,1)); amax = fmaxf(amax, __shfl_xor(amax,2));
  float am = fmaxf(amax, EPSQ);
  float gamma = QBC / am;
  if (g == 0){ ig[n] = am * (1.0f/QBC); mr[n] = make_float2(mean, rs); }
  #pragma unroll
  for (int i4 = 0; i4 < 4; i4++){
    float q0 = fminf(fmaxf(rintf(xnv[4*i4+0]*gamma), -128.f), 127.f);
    float q1 = fminf(fmaxf(rintf(xnv[4*i4+1]*gamma), -128.f), 127.f);
    float q2 = fminf(fmaxf(rintf(xnv[4*i4+2]*gamma), -128.f), 127.f);
    float q3 = fminf(fmaxf(rintf(xnv[4*i4+3]*gamma), -128.f), 127.f);
    Xp[c][g*4+i4] = pack4(q0,q1,q2,q3);
  }
  __syncthreads();

  int r0 = (t >> 4) << 2, c0 = (t & 15) << 2;
  #pragma unroll
  for (int m = 0; m < 3; m++){
    int acc[4][4] = {};
    #pragma unroll
    for (int kp = 0; kp < 16; kp++){
      int av[4], bv[4];
      #pragma unroll
      for (int i = 0; i < 4; i++) av[i] = Xp[r0+i][kp];
      #pragma unroll
      for (int j = 0; j < 4; j++) bv[j] = Wp[m][c0+j][kp];
      #pragma unroll
      for (int i = 0; i < 4; i++)
        #pragma unroll
        for (int j = 0; j < 4; j++)
          acc[i][j] = SDOT4(av[i], bv[j], acc[i][j]);
    }
    short* op = ((m==0)?q16:(m==1)?k16:v16) + (long)blockIdx.x*4096;
    #pragma unroll
    for (int i = 0; i < 4; i++){
      short4 s4;
      s4.x = (short)acc[i][0]; s4.y = (short)acc[i][1];
      s4.z = (short)acc[i][2]; s4.w = (short)acc[i][3];
      *(short4*)&op[(r0+i)*64 + c0] = s4;
    }
  }
}

// ---------------- K3: scores += (Q@K^T)/8; 32 chunks per batch, int16 reconstruct --------------
__global__ __launch_bounds__(256,4) void k_qk(
    const short* __restrict__ q16, const short* __restrict__ k16,
    const float* __restrict__ ig, const float* __restrict__ beta5,
    const float* __restrict__ qbias, const float* __restrict__ kbias,
    float* __restrict__ sco){
  __shared__ float Qs[64][68];
  __shared__ float Kt[64][68];
  __shared__ float qbs[64], kbs[64];
  int t = threadIdx.x;
  int b = blockIdx.x >> 5, ch = blockIdx.x & 31;
  int c = t >> 2, g = t & 3;
  int r0 = (t >> 4) << 2, c0 = (t & 15) << 2;
  if (t < 64){ qbs[t] = qbias[t]; kbs[t] = kbias[t]; }
  float bq = beta5[0], bk = beta5[1];
  const short* qbase = q16 + (long)b*262144 + (long)c*4096;
  const short* kbase = k16 + (long)b*262144 + (long)c*4096;
  float acc[4][4] = {};
  for (int sub = 0; sub < 2; sub++){
    int t0 = ch*128 + sub*64 + g*16;
    int4 qa = *(const int4*)(qbase + t0);
    int4 qb2 = *(const int4*)(qbase + t0 + 8);
    int4 ka = *(const int4*)(kbase + t0);
    int4 kb2 = *(const int4*)(kbase + t0 + 8);
    float sgi = ig[b*4096 + c*64 + ch*2 + sub];
    float sq = bq * sgi, sk = bk * sgi;
    __syncthreads();
    int qi[8] = {qa.x,qa.y,qa.z,qa.w,qb2.x,qb2.y,qb2.z,qb2.w};
    int ki[8] = {ka.x,ka.y,ka.z,ka.w,kb2.x,kb2.y,kb2.z,kb2.w};
    #pragma unroll
    for (int w2 = 0; w2 < 8; w2++){
      int e0 = g*16 + 2*w2, e1 = e0 + 1;
      Qs[c][e0] = (float)((qi[w2]<<16)>>16)*sq + qbs[e0];
      Qs[c][e1] = (float)( qi[w2]>>16      )*sq + qbs[e1];
      Kt[e0][c] = (float)((ki[w2]<<16)>>16)*sk + kbs[e0];
      Kt[e1][c] = (float)( ki[w2]>>16      )*sk + kbs[e1];
    }
    __syncthreads();
    for (int k4 = 0; k4 < 64; k4 += 4){
      float4 a[4], bv[4];
      #pragma unroll
      for (int i = 0; i < 4; i++) a[i] = *(const float4*)&Qs[r0+i][k4];
      #pragma unroll
      for (int kk = 0; kk < 4; kk++) bv[kk] = *(const float4*)&Kt[k4+kk][c0];
      #pragma unroll
      for (int i = 0; i < 4; i++){
        const float* ap = (const float*)&a[i];
        #pragma unroll
        for (int kk = 0; kk < 4; kk++){
          float av = ap[kk];
          acc[i][0] = fmaf(av, bv[kk].x, acc[i][0]);
          acc[i][1] = fmaf(av, bv[kk].y, acc[i][1]);
          acc[i][2] = fmaf(av, bv[kk].z, acc[i][2]);
          acc[i][3] = fmaf(av, bv[kk].w, acc[i][3]);
        }
      }
    }
  }
  float* sc = sco + b*4096;
  #pragma unroll
  for (int i = 0; i < 4; i++)
    #pragma unroll
    for (int j = 0; j < 4; j++)
      atomicAdd(&sc[(r0+i)*64 + c0 + j], acc[i][j]*0.125f);
}

// ---------------- K4: softmax + PV + LN2 + res + LN3 + FFN1 + LN4 + FFN2 -----------------------
__global__ __launch_bounds__(256,3) void k_epi(const float* __restrict__ x,
    const short* __restrict__ v16, const float* __restrict__ sco,
    const float2* __restrict__ mr, const float* __restrict__ ig,
    const float* __restrict__ beta5, const int* __restrict__ wpk,
    const float* ln1g, const float* ln1b,
    const float* ln2g, const float* ln2b, const float* ln3g, const float* ln3b,
    const float* ln4g, const float* ln4b, const float* __restrict__ vbias,
    const float* f1b, const float* f2b, float* __restrict__ out){
  __shared__ float B1[64][68];
  __shared__ float B2[64][68];
  __shared__ int Wp[2][64][17];
  __shared__ int Xp[64][17];
  __shared__ float gam1[64], gam2[64];
  int t = threadIdx.x;
  int b = blockIdx.x >> 6;
  int s0 = (blockIdx.x & 63) << 6;
  float bv_ = beta5[2];
  for (int i = t; i < 4096; i += 256){
    int r = i >> 6, cc = i & 63;
    B1[r][cc] = sco[b*4096 + i];
    float sv = bv_ * ig[b*4096 + r*64 + (s0 >> 6)];
    B2[r][cc] = (float)v16[(long)b*262144 + (long)r*4096 + s0 + cc] * sv + vbias[cc];
  }
  for (int i = t; i < 2048; i += 256){
    int m = i >> 10, rem = i & 1023;
    Wp[m][rem>>4][rem&15] = wpk[(3+m)*1024 + rem];
  }
  __syncthreads();
  int c = t >> 2, g = t & 3;
  // softmax over f (cols of B1 row c)
  {
    float sv[16];
    #pragma unroll
    for (int i4 = 0; i4 < 4; i4++){
      float4 f = *(const float4*)&B1[c][g*16 + 4*i4];
      sv[4*i4+0]=f.x; sv[4*i4+1]=f.y; sv[4*i4+2]=f.z; sv[4*i4+3]=f.w;
    }
    float mx = sv[0];
    #pragma unroll
    for (int i = 1; i < 16; i++) mx = fmaxf(mx, sv[i]);
    mx = fmaxf(mx, __shfl_xor(mx,1)); mx = fmaxf(mx, __shfl_xor(mx,2));
    float se = 0.f;
    #pragma unroll
    for (int i = 0; i < 16; i++){ sv[i] = expf(sv[i]-mx); se += sv[i]; }
    se += __shfl_xor(se,1); se += __shfl_xor(se,2);
    float inv = 1.0f/se;
    #pragma unroll
    for (int i4 = 0; i4 < 4; i4++)
      *(float4*)&B1[c][g*16+4*i4] = make_float4(sv[4*i4]*inv, sv[4*i4+1]*inv, sv[4*i4+2]*inv, sv[4*i4+3]*inv);
  }
  __syncthreads();
  int r0 = (t >> 4) << 2, c0 = (t & 15) << 2;
  // P1: Ov = attn @ Vt
  float acc[4][4] = {};
  for (int k4 = 0; k4 < 64; k4 += 4){
    float4 a[4], bv[4];
    #pragma unroll
    for (int i = 0; i < 4; i++) a[i] = *(const float4*)&B1[r0+i][k4];
    #pragma unroll
    for (int kk = 0; kk < 4; kk++) bv[kk] = *(const float4*)&B2[k4+kk][c0];
    #pragma unroll
    for (int i = 0; i < 4; i++){
      const float* ap = (const float*)&a[i];
      #pragma unroll
      for (int kk = 0; kk < 4; kk++){
        float av = ap[kk];
        acc[i][0] = fmaf(av, bv[kk].x, acc[i][0]);
        acc[i][1] = fmaf(av, bv[kk].y, acc[i][1]);
        acc[i][2] = fmaf(av, bv[kk].z, acc[i][2]);
        acc[i][3] = fmaf(av, bv[kk].w, acc[i][3]);
      }
    }
  }
  __syncthreads();
  #pragma unroll
  for (int i = 0; i < 4; i++)
    #pragma unroll
    for (int j = 0; j < 4; j++) B1[c0+j][r0+i] = acc[i][j];   // Ov^T
  __syncthreads();
  // P3: recompute xn; d = attnout - xn; LN2; +x -> r2 (B2); LN3 -> quant -> Xp
  long n = (long)b*4096 + s0 + c;
  const float* xp = x + n*64 + g*16;
  float xa[16];
  #pragma unroll
  for (int i4 = 0; i4 < 4; i4++){
    float4 f = ((const float4*)xp)[i4];
    xa[4*i4+0]=f.x; xa[4*i4+1]=f.y; xa[4*i4+2]=f.z; xa[4*i4+3]=f.w;
  }
  float2 m2 = mr[n];
  float d[16];
  #pragma unroll
  for (int i4 = 0; i4 < 4; i4++){
    float4 f = *(const float4*)&B1[c][g*16 + 4*i4];
    d[4*i4+0]=f.x; d[4*i4+1]=f.y; d[4*i4+2]=f.z; d[4*i4+3]=f.w;
  }
  #pragma unroll
  for (int i = 0; i < 16; i++){
    float xn_i = (xa[i]-m2.x)*m2.y*ln1g[g*16+i] + ln1b[g*16+i];
    d[i] -= xn_i;
  }
  float s = 0.f;
  #pragma unroll
  for (int i = 0; i < 16; i++) s += d[i];
  s += __shfl_xor(s,1); s += __shfl_xor(s,2);
  float mean = s*(1.0f/64.0f);
  float vs = 0.f;
  #pragma unroll
  for (int i = 0; i < 16; i++){ float dd = d[i]-mean; vs += dd*dd; }
  vs += __shfl_xor(vs,1); vs += __shfl_xor(vs,2);
  float rs = rsqrtf(vs*(1.0f/64.0f) + LNE);
  float r2[16];
  #pragma unroll
  for (int i = 0; i < 16; i++){
    float t2 = (d[i]-mean)*rs*ln2g[g*16+i] + ln2b[g*16+i];
    r2[i] = t2 + xa[i];
  }
  #pragma unroll
  for (int i4 = 0; i4 < 4; i4++)
    *(float4*)&B2[c][g*16+4*i4] = make_float4(r2[4*i4],r2[4*i4+1],r2[4*i4+2],r2[4*i4+3]);
  s = 0.f;
  #pragma unroll
  for (int i = 0; i < 16; i++) s += r2[i];
  s += __shfl_xor(s,1); s += __shfl_xor(s,2);
  float mean3 = s*(1.0f/64.0f);
  vs = 0.f;
  #pragma unroll
  for (int i = 0; i < 16; i++){ float dd = r2[i]-mean3; vs += dd*dd; }
  vs += __shfl_xor(vs,1); vs += __shfl_xor(vs,2);
  float rs3 = rsqrtf(vs*(1.0f/64.0f) + LNE);
  float u16v[16]; float amax = 0.f;
  #pragma unroll
  for (int i = 0; i < 16; i++){
    float u = (r2[i]-mean3)*rs3*ln3g[g*16+i] + ln3b[g*16+i];
    u16v[i] = u; amax = fmaxf(amax, fabsf(u));
  }
  amax = fmaxf(amax, __shfl_xor(amax,1)); amax = fmaxf(amax, __shfl_xor(amax,2));
  float gamma = QBC / fmaxf(amax, EPSQ);
  #pragma unroll
  for (int i4 = 0; i4 < 4; i4++){
    float q0 = fminf(fmaxf(rintf(u16v[4*i4+0]*gamma), -128.f), 127.f);
    float q1 = fminf(fmaxf(rintf(u16v[4*i4+1]*gamma), -128.f), 127.f);
    float q2 = fminf(fmaxf(rintf(u16v[4*i4+2]*gamma), -128.f), 127.f);
    float q3 = fminf(fmaxf(rintf(u16v[4*i4+3]*gamma), -128.f), 127.f);
    Xp[c][g*4+i4] = pack4(q0,q1,q2,q3);
  }
  if (g == 0) gam1[c] = gamma;
  __syncthreads();
  // P4: FFN1 (int8)
  int ac2[4][4] = {};
  #pragma unroll
  for (int kp = 0; kp < 16; kp++){
    int av[4], bv2[4];
    #pragma unroll
    for (int i = 0; i < 4; i++) av[i] = Xp[r0+i][kp];
    #pragma unroll
    for (int j = 0; j < 4; j++) bv2[j] = Wp[0][c0+j][kp];
    #pragma unroll
    for (int i = 0; i < 4; i++)
      #pragma unroll
      for (int j = 0; j < 4; j++)
        ac2[i][j] = SDOT4(av[i], bv2[j], ac2[i][j]);
  }
  __syncthreads();
  float beta1 = beta5[3], beta2 = beta5[4];
  #pragma unroll
  for (int i = 0; i < 4; i++){
    float sc = beta1 / gam1[r0+i];
    #pragma unroll
    for (int j = 0; j < 4; j++)
      B1[r0+i][c0+j] = gelu_f((float)ac2[i][j]*sc + f1b[c0+j]);
  }
  __syncthreads();
  // P5: LN4 + quant
  float gl[16];
  #pragma unroll
  for (int i4 = 0; i4 < 4; i4++){
    float4 f = *(const float4*)&B1[c][g*16 + 4*i4];
    gl[4*i4+0]=f.x; gl[4*i4+1]=f.y; gl[4*i4+2]=f.z; gl[4*i4+3]=f.w;
  }
  s = 0.f;
  #pragma unroll
  for (int i = 0; i < 16; i++) s += gl[i];
  s += __shfl_xor(s,1); s += __shfl_xor(s,2);
  float mean4 = s*(1.0f/64.0f);
  vs = 0.f;
  #pragma unroll
  for (int i = 0; i < 16; i++){ float dd = gl[i]-mean4; vs += dd*dd; }
  vs += __shfl_xor(vs,1); vs += __shfl_xor(vs,2);
  float rs4 = rsqrtf(vs*(1.0f/64.0f) + LNE);
  amax = 0.f;
  #pragma unroll
  for (int i = 0; i < 16; i++){
    float u = (gl[i]-mean4)*rs4*ln4g[g*16+i] + ln4b[g*16+i];
    u16v[i] = u; amax = fmaxf(amax, fabsf(u));
  }
  amax = fmaxf(amax, __shfl_xor(amax,1)); amax = fmaxf(amax, __shfl_xor(amax,2));
  float gamma2 = QBC / fmaxf(amax, EPSQ);
  #pragma unroll
  for (int i4 = 0; i4 < 4; i4++){
    float q0 = fminf(fmaxf(rintf(u16v[4*i4+0]*gamma2), -128.f), 127.f);
    float q1 = fminf(fmaxf(rintf(u16v[4*i4+1]*gamma2), -128.f), 127.f);
    float q2 = fminf(fmaxf(rintf(u16v[4*i4+2]*gamma2), -128.f), 127.f);
    float q3 = fminf(fmaxf(rintf(u16v[4*i4+3]*gamma2), -128.f), 127.f);
    Xp[c][g*4+i4] = pack4(q0,q1,q2,q3);
  }
  if (g == 0) gam2[c] = gamma2;
  __syncthreads();
  // P6: FFN2 (int8) + final add
  int ac3[4][4] = {};
  #pragma unroll
  for (int kp = 0; kp < 16; kp++){
    int av[4], bv2[4];
    #pragma unroll
    for (int i = 0; i < 4; i++) av[i] = Xp[r0+i][kp];
    #pragma unroll
    for (int j = 0; j < 4; j++) bv2[j] = Wp[1][c0+j][kp];
    #pragma unroll
    for (int i = 0; i < 4; i++)
      #pragma unroll
      for (int j = 0; j < 4; j++)
        ac3[i][j] = SDOT4(av[i], bv2[j], ac3[i][j]);
  }
  float4 bf = *(const float4*)&f2b[c0];
  #pragma unroll
  for (int i = 0; i < 4; i++){
    float sc = beta2 / gam2[r0+i];
    float4 rr = *(const float4*)&B2[r0+i][c0];
    f32x4 o;
    o.x = (float)ac3[i][0]*sc + bf.x + rr.x;
    o.y = (float)ac3[i][1]*sc + bf.y + rr.y;
    o.z = (float)ac3[i][2]*sc + bf.z + rr.z;
    o.w = (float)ac3[i][3]*sc + bf.w + rr.w;
    __builtin_nontemporal_store(o, (f32x4*)&out[((long)b*4096 + s0 + r0 + i)*64 + c0]);
  }
}

extern "C" void kernel_launch(void* const* d_in, const int* in_sizes, int n_in,
                              void* d_out, int out_size, void* d_ws, size_t ws_size,
                              hipStream_t stream){
  const float* x    = (const float*)d_in[0];
  const float* it2  = (const float*)d_in[1];
  const float* qw   = (const float*)d_in[2];
  const float* qb   = (const float*)d_in[3];
  const float* kw   = (const float*)d_in[4];
  const float* kb   = (const float*)d_in[5];
  const float* vw   = (const float*)d_in[6];
  const float* vb   = (const float*)d_in[7];
  const float* f1w  = (const float*)d_in[8];
  const float* f1b  = (const float*)d_in[9];
  const float* f2w  = (const float*)d_in[10];
  const float* f2b  = (const float*)d_in[11];
  const float* c1w  = (const float*)d_in[12];
  const float* c1b  = (const float*)d_in[13];
  const float* c2w  = (const float*)d_in[14];
  const float* c2b  = (const float*)d_in[15];
  const float* c3w  = (const float*)d_in[16];
  const float* c3b  = (const float*)d_in[17];
  const float* ln1g = (const float*)d_in[18];
  const float* ln1b = (const float*)d_in[19];
  const float* ln2g = (const float*)d_in[20];
  const float* ln2b = (const float*)d_in[21];
  const float* ln3g = (const float*)d_in[22];
  const float* ln3b = (const float*)d_in[23];
  const float* ln4g = (const float*)d_in[24];
  const float* ln4b = (const float*)d_in[25];
  float* out = (float*)d_out;

  char* w = (char*)d_ws;
  int*    wpk   = (int*)(w + OFF_WPK);
  float*  beta5 = (float*)(w + OFF_BETA);
  float*  ig    = (float*)(w + OFF_IG);
  float2* mr    = (float2*)(w + OFF_MR);
  short*  q16   = (short*)(w + OFF_Q);
  short*  k16   = (short*)(w + OFF_K);
  short*  v16   = (short*)(w + OFF_V);
  float*  sco   = (float*)(w + OFF_SC);

  hipLaunchKernelGGL(k_prep, dim3(37),   dim3(1024), 0, stream,
                     qw, kw, vw, f1w, f2w, it2, c1w, c1b, c2w, c2b, c3w, c3b, wpk, beta5, sco);
  hipLaunchKernelGGL(k_qkv,  dim3(2048), dim3(256), 0, stream,
                     x, ln1g, ln1b, wpk, mr, ig, q16, k16, v16);
  hipLaunchKernelGGL(k_qk,   dim3(1024), dim3(256), 0, stream,
                     q16, k16, ig, beta5, qb, kb, sco);
  hipLaunchKernelGGL(k_epi,  dim3(2048), dim3(256), 0, stream,
                     x, v16, sco, mr, ig, beta5, wpk, ln1g, ln1b,
                     ln2g, ln2b, ln3g, ln3b, ln4g, ln4b, vb, f1b, f2b, out);
}

// Round 9
// 321.794 us; speedup vs baseline: 1.2740x; 1.2740x over previous
//
#include <hip/hip_runtime.h>

#define EPSQ 1e-8f
#define QBC  127.0f
#define LNE  1e-5f

typedef float f32x4 __attribute__((ext_vector_type(4)));

// ---- sdot4: int8x4 dot product ----
#if defined(__has_builtin)
#  if __has_builtin(__builtin_amdgcn_sdot4)
#    define SDOT4(a,b,c) __builtin_amdgcn_sdot4((a),(b),(c),false)
#  endif
#endif
#ifndef SDOT4
__device__ __forceinline__ int sdot4_sw(int a, int b, int c){
  c += ((a<<24)>>24) * ((b<<24)>>24);
  c += ((a<<16)>>24) * ((b<<16)>>24);
  c += ((a<< 8)>>24) * ((b<< 8)>>24);
  c += ( a>>24     ) * ( b>>24     );
  return c;
}
#  define SDOT4(a,b,c) sdot4_sw((a),(b),(c))
#endif

// ws byte offsets
constexpr size_t OFF_WPK  = 0;                       // 5*1024 ints (packed ternary rows)
constexpr size_t OFF_BETA = 20480;                   // 5 floats (pad)
constexpr size_t OFF_IG   = 20544;                   // 131072 floats: amax/127 per row
constexpr size_t OFF_MR   = OFF_IG + 524288;         // 131072 float2: (mean, rsqrt) per row
constexpr size_t OFF_Q    = OFF_MR + 1048576;        // 8388608 shorts
constexpr size_t OFF_K    = OFF_Q  + 16777216;
constexpr size_t OFF_V    = OFF_K  + 16777216;
constexpr size_t OFF_SC   = OFF_V  + 16777216;       // 131072 floats (scores)

__device__ __forceinline__ float gelu_f(float v){
  return 0.5f * v * (1.0f + erff(v * 0.70710678118654752f));
}
__device__ __forceinline__ int pack4(float q0, float q1, float q2, float q3){
  return ((int)q0 & 255) | (((int)q1 & 255) << 8) | (((int)q2 & 255) << 16) | (((int)q3 & 255) << 24);
}

// ---------------- K1: blocks 0-4 weight quantize+pack; blocks 5-36 conv path ------------------
__global__ __launch_bounds__(1024) void k_prep(
    const float* qw, const float* kw, const float* vw, const float* f1w, const float* f2w,
    const float* it2, const float* c1w, const float* c1b, const float* c2w, const float* c2b,
    const float* c3w, const float* c3b, int* __restrict__ wpk, float* __restrict__ beta5,
    float* __restrict__ sco){
  __shared__ float smem[1024 + 2*64*65];
  int t = threadIdx.x;
  if (blockIdx.x < 5){
    int m = blockIdx.x;
    const float* w = (m==0)?qw:(m==1)?kw:(m==2)?vw:(m==3)?f1w:f2w;
    float* red = smem;
    float s = 0.f;
    for (int i = t; i < 4096; i += 1024) s += fabsf(w[i]);
    red[t] = s; __syncthreads();
    for (int o = 512; o > 0; o >>= 1){ if (t < o) red[t] += red[t+o]; __syncthreads(); }
    float beta = fmaxf(red[0] * (1.0f/4096.0f), EPSQ);
    if (t == 0) beta5[m] = beta;
    int* dst = wpk + m*1024;
    if (t < 1024){
      int row = t >> 4, kp = t & 15;
      int v = 0;
      #pragma unroll
      for (int j = 0; j < 4; j++){
        float q = rintf(w[row*64 + kp*4 + j] / beta);
        q = fminf(fmaxf(q, -1.f), 1.f);
        v |= ((int)q & 255) << (8*j);
      }
      dst[t] = v;
    }
  } else {
    int b = blockIdx.x - 5;
    float* in32 = smem;
    float (*Aa)[65] = (float(*)[65])(smem + 1024);
    float (*Bb)[65] = (float(*)[65])(smem + 1024 + 64*65);
    for (int i = t; i < 1024; i += 1024) in32[i] = it2[b*1024 + i];
    __syncthreads();
    for (int p = t; p < 4096; p += 1024){
      int i = p >> 6, j = p & 63;
      float si = 0.5f*i - 0.25f, fi = floorf(si), wi = si - fi;
      int i0 = min(max((int)fi, 0), 31), i1 = min(max((int)fi + 1, 0), 31);
      float sj = 0.5f*j - 0.25f, fj = floorf(sj), wj = sj - fj;
      int j0 = min(max((int)fj, 0), 31), j1 = min(max((int)fj + 1, 0), 31);
      float v00 = in32[i0*32+j0], v01 = in32[i0*32+j1];
      float v10 = in32[i1*32+j0], v11 = in32[i1*32+j1];
      Aa[i][j] = (1.f-wi)*((1.f-wj)*v00 + wj*v01) + wi*((1.f-wj)*v10 + wj*v11);
    }
    __syncthreads();
    {
      float w9[9]; for (int q2=0;q2<9;q2++) w9[q2]=c1w[q2]; float bb = c1b[0];
      for (int p = t; p < 4096; p += 1024){
        int i = p>>6, j = p&63; float s = bb;
        #pragma unroll
        for (int di=-1; di<=1; di++)
          #pragma unroll
          for (int dj=-1; dj<=1; dj++){
            int ii=i+di, jj=j+dj;
            if (ii>=0 && ii<64 && jj>=0 && jj<64) s += w9[(di+1)*3+dj+1]*Aa[ii][jj];
          }
        Bb[i][j] = gelu_f(s);
      }
    }
    __syncthreads();
    {
      float w9[9]; for (int q2=0;q2<9;q2++) w9[q2]=c2w[q2]; float bb = c2b[0];
      for (int p = t; p < 4096; p += 1024){
        int i = p>>6, j = p&63; float s = bb;
        #pragma unroll
        for (int di=-1; di<=1; di++)
          #pragma unroll
          for (int dj=-1; dj<=1; dj++){
            int ii=i+di, jj=j+dj;
            if (ii>=0 && ii<64 && jj>=0 && jj<64) s += w9[(di+1)*3+dj+1]*Bb[ii][jj];
          }
        Aa[i][j] = gelu_f(s);
      }
    }
    __syncthreads();
    {
      float w9[9]; for (int q2=0;q2<9;q2++) w9[q2]=c3w[q2]; float bb = c3b[0];
      for (int p = t; p < 4096; p += 1024){
        int i = p>>6, j = p&63; float s = bb;
        #pragma unroll
        for (int di=-1; di<=1; di++)
          #pragma unroll
          for (int dj=-1; dj<=1; dj++){
            int ii=i+di, jj=j+dj;
            if (ii>=0 && ii<64 && jj>=0 && jj<64) s += w9[(di+1)*3+dj+1]*Aa[ii][jj];
          }
        sco[b*4096 + p] = gelu_f(s);
      }
    }
  }
}

// ---------------- K2: LN1 + quant + QKV int8 GEMM -> int16 accums ------------------------------
__global__ __launch_bounds__(256,4) void k_qkv(const float* __restrict__ x,
    const float* __restrict__ ln1g, const float* __restrict__ ln1b,
    const int* __restrict__ wpk, float2* __restrict__ mr, float* __restrict__ ig,
    short* __restrict__ q16, short* __restrict__ k16, short* __restrict__ v16){
  __shared__ int Wp[3][64][17];
  __shared__ int Xp[64][17];
  int t = threadIdx.x;
  for (int i = t; i < 3072; i += 256){
    int m = i >> 10, rem = i & 1023;
    Wp[m][rem>>4][rem&15] = wpk[i];
  }
  int c = t >> 2, g = t & 3;
  long n = (long)blockIdx.x * 64 + c;
  const float* xr = x + n*64 + g*16;
  float xv[16];
  #pragma unroll
  for (int i4 = 0; i4 < 4; i4++){
    float4 f = ((const float4*)xr)[i4];
    xv[4*i4+0]=f.x; xv[4*i4+1]=f.y; xv[4*i4+2]=f.z; xv[4*i4+3]=f.w;
  }
  float s = 0.f;
  #pragma unroll
  for (int i = 0; i < 16; i++) s += xv[i];
  s += __shfl_xor(s,1); s += __shfl_xor(s,2);
  float mean = s * (1.0f/64.0f);
  float vs = 0.f;
  #pragma unroll
  for (int i = 0; i < 16; i++){ float dd = xv[i]-mean; vs += dd*dd; }
  vs += __shfl_xor(vs,1); vs += __shfl_xor(vs,2);
  float rs = rsqrtf(vs*(1.0f/64.0f) + LNE);
  float xnv[16]; float amax = 0.f;
  #pragma unroll
  for (int i = 0; i < 16; i++){
    float u = (xv[i]-mean)*rs*ln1g[g*16+i] + ln1b[g*16+i];
    xnv[i] = u; amax = fmaxf(amax, fabsf(u));
  }
  amax = fmaxf(amax, __shfl_xor(amax,1)); amax = fmaxf(amax, __shfl_xor(amax,2));
  float am = fmaxf(amax, EPSQ);
  float gamma = QBC / am;
  if (g == 0){ ig[n] = am * (1.0f/QBC); mr[n] = make_float2(mean, rs); }
  #pragma unroll
  for (int i4 = 0; i4 < 4; i4++){
    float q0 = fminf(fmaxf(rintf(xnv[4*i4+0]*gamma), -128.f), 127.f);
    float q1 = fminf(fmaxf(rintf(xnv[4*i4+1]*gamma), -128.f), 127.f);
    float q2 = fminf(fmaxf(rintf(xnv[4*i4+2]*gamma), -128.f), 127.f);
    float q3 = fminf(fmaxf(rintf(xnv[4*i4+3]*gamma), -128.f), 127.f);
    Xp[c][g*4+i4] = pack4(q0,q1,q2,q3);
  }
  __syncthreads();

  int r0 = (t >> 4) << 2, c0 = (t & 15) << 2;
  #pragma unroll
  for (int m = 0; m < 3; m++){
    int acc[4][4] = {};
    #pragma unroll
    for (int kp = 0; kp < 16; kp++){
      int av[4], bv[4];
      #pragma unroll
      for (int i = 0; i < 4; i++) av[i] = Xp[r0+i][kp];
      #pragma unroll
      for (int j = 0; j < 4; j++) bv[j] = Wp[m][c0+j][kp];
      #pragma unroll
      for (int i = 0; i < 4; i++)
        #pragma unroll
        for (int j = 0; j < 4; j++)
          acc[i][j] = SDOT4(av[i], bv[j], acc[i][j]);
    }
    short* op = ((m==0)?q16:(m==1)?k16:v16) + (long)blockIdx.x*4096;
    #pragma unroll
    for (int i = 0; i < 4; i++){
      short4 s4;
      s4.x = (short)acc[i][0]; s4.y = (short)acc[i][1];
      s4.z = (short)acc[i][2]; s4.w = (short)acc[i][3];
      *(short4*)&op[(r0+i)*64 + c0] = s4;
    }
  }
}

// ---------------- K3: scores += (Q@K^T)/8; 32 chunks per batch, int16 reconstruct --------------
__global__ __launch_bounds__(256,4) void k_qk(
    const short* __restrict__ q16, const short* __restrict__ k16,
    const float* __restrict__ ig, const float* __restrict__ beta5,
    const float* __restrict__ qbias, const float* __restrict__ kbias,
    float* __restrict__ sco){
  __shared__ float Qs[64][68];
  __shared__ float Kt[64][68];
  __shared__ float qbs[64], kbs[64];
  int t = threadIdx.x;
  int b = blockIdx.x >> 5, ch = blockIdx.x & 31;
  int c = t >> 2, g = t & 3;
  int r0 = (t >> 4) << 2, c0 = (t & 15) << 2;
  if (t < 64){ qbs[t] = qbias[t]; kbs[t] = kbias[t]; }
  float bq = beta5[0], bk = beta5[1];
  const short* qbase = q16 + (long)b*262144 + (long)c*4096;
  const short* kbase = k16 + (long)b*262144 + (long)c*4096;
  float acc[4][4] = {};
  for (int sub = 0; sub < 2; sub++){
    int t0 = ch*128 + sub*64 + g*16;
    int4 qa = *(const int4*)(qbase + t0);
    int4 qb2 = *(const int4*)(qbase + t0 + 8);
    int4 ka = *(const int4*)(kbase + t0);
    int4 kb2 = *(const int4*)(kbase + t0 + 8);
    float sgi = ig[b*4096 + c*64 + ch*2 + sub];
    float sq = bq * sgi, sk = bk * sgi;
    __syncthreads();
    int qi[8] = {qa.x,qa.y,qa.z,qa.w,qb2.x,qb2.y,qb2.z,qb2.w};
    int ki[8] = {ka.x,ka.y,ka.z,ka.w,kb2.x,kb2.y,kb2.z,kb2.w};
    #pragma unroll
    for (int w2 = 0; w2 < 8; w2++){
      int e0 = g*16 + 2*w2, e1 = e0 + 1;
      Qs[c][e0] = (float)((qi[w2]<<16)>>16)*sq + qbs[e0];
      Qs[c][e1] = (float)( qi[w2]>>16      )*sq + qbs[e1];
      Kt[e0][c] = (float)((ki[w2]<<16)>>16)*sk + kbs[e0];
      Kt[e1][c] = (float)( ki[w2]>>16      )*sk + kbs[e1];
    }
    __syncthreads();
    for (int k4 = 0; k4 < 64; k4 += 4){
      float4 a[4], bv[4];
      #pragma unroll
      for (int i = 0; i < 4; i++) a[i] = *(const float4*)&Qs[r0+i][k4];
      #pragma unroll
      for (int kk = 0; kk < 4; kk++) bv[kk] = *(const float4*)&Kt[k4+kk][c0];
      #pragma unroll
      for (int i = 0; i < 4; i++){
        const float* ap = (const float*)&a[i];
        #pragma unroll
        for (int kk = 0; kk < 4; kk++){
          float av = ap[kk];
          acc[i][0] = fmaf(av, bv[kk].x, acc[i][0]);
          acc[i][1] = fmaf(av, bv[kk].y, acc[i][1]);
          acc[i][2] = fmaf(av, bv[kk].z, acc[i][2]);
          acc[i][3] = fmaf(av, bv[kk].w, acc[i][3]);
        }
      }
    }
  }
  float* sc = sco + b*4096;
  #pragma unroll
  for (int i = 0; i < 4; i++)
    #pragma unroll
    for (int j = 0; j < 4; j++)
      atomicAdd(&sc[(r0+i)*64 + c0 + j], acc[i][j]*0.125f);
}

// ---------------- K4: softmax + PV + LN2 + res + LN3 + FFN1 + LN4 + FFN2 -----------------------
__global__ __launch_bounds__(256,3) void k_epi(const float* __restrict__ x,
    const short* __restrict__ v16, const float* __restrict__ sco,
    const float2* __restrict__ mr, const float* __restrict__ ig,
    const float* __restrict__ beta5, const int* __restrict__ wpk,
    const float* ln1g, const float* ln1b,
    const float* ln2g, const float* ln2b, const float* ln3g, const float* ln3b,
    const float* ln4g, const float* ln4b, const float* __restrict__ vbias,
    const float* f1b, const float* f2b, float* __restrict__ out){
  __shared__ float B1[64][68];
  __shared__ float B2[64][68];
  __shared__ int Wp[2][64][17];
  __shared__ int Xp[64][17];
  __shared__ float gam1[64], gam2[64];
  int t = threadIdx.x;
  int b = blockIdx.x >> 6;
  int s0 = (blockIdx.x & 63) << 6;
  float bv_ = beta5[2];
  for (int i = t; i < 4096; i += 256){
    int r = i >> 6, cc = i & 63;
    B1[r][cc] = sco[b*4096 + i];
    float sv = bv_ * ig[b*4096 + r*64 + (s0 >> 6)];
    B2[r][cc] = (float)v16[(long)b*262144 + (long)r*4096 + s0 + cc] * sv + vbias[cc];
  }
  for (int i = t; i < 2048; i += 256){
    int m = i >> 10, rem = i & 1023;
    Wp[m][rem>>4][rem&15] = wpk[(3+m)*1024 + rem];
  }
  __syncthreads();
  int c = t >> 2, g = t & 3;
  // softmax over f (cols of B1 row c)
  {
    float sv[16];
    #pragma unroll
    for (int i4 = 0; i4 < 4; i4++){
      float4 f = *(const float4*)&B1[c][g*16 + 4*i4];
      sv[4*i4+0]=f.x; sv[4*i4+1]=f.y; sv[4*i4+2]=f.z; sv[4*i4+3]=f.w;
    }
    float mx = sv[0];
    #pragma unroll
    for (int i = 1; i < 16; i++) mx = fmaxf(mx, sv[i]);
    mx = fmaxf(mx, __shfl_xor(mx,1)); mx = fmaxf(mx, __shfl_xor(mx,2));
    float se = 0.f;
    #pragma unroll
    for (int i = 0; i < 16; i++){ sv[i] = expf(sv[i]-mx); se += sv[i]; }
    se += __shfl_xor(se,1); se += __shfl_xor(se,2);
    float inv = 1.0f/se;
    #pragma unroll
    for (int i4 = 0; i4 < 4; i4++)
      *(float4*)&B1[c][g*16+4*i4] = make_float4(sv[4*i4]*inv, sv[4*i4+1]*inv, sv[4*i4+2]*inv, sv[4*i4+3]*inv);
  }
  __syncthreads();
  int r0 = (t >> 4) << 2, c0 = (t & 15) << 2;
  // P1: Ov = attn @ Vt
  float acc[4][4] = {};
  for (int k4 = 0; k4 < 64; k4 += 4){
    float4 a[4], bv[4];
    #pragma unroll
    for (int i = 0; i < 4; i++) a[i] = *(const float4*)&B1[r0+i][k4];
    #pragma unroll
    for (int kk = 0; kk < 4; kk++) bv[kk] = *(const float4*)&B2[k4+kk][c0];
    #pragma unroll
    for (int i = 0; i < 4; i++){
      const float* ap = (const float*)&a[i];
      #pragma unroll
      for (int kk = 0; kk < 4; kk++){
        float av = ap[kk];
        acc[i][0] = fmaf(av, bv[kk].x, acc[i][0]);
        acc[i][1] = fmaf(av, bv[kk].y, acc[i][1]);
        acc[i][2] = fmaf(av, bv[kk].z, acc[i][2]);
        acc[i][3] = fmaf(av, bv[kk].w, acc[i][3]);
      }
    }
  }
  __syncthreads();
  #pragma unroll
  for (int i = 0; i < 4; i++)
    #pragma unroll
    for (int j = 0; j < 4; j++) B1[c0+j][r0+i] = acc[i][j];   // Ov^T
  __syncthreads();
  // P3: recompute xn; d = attnout - xn; LN2; +x -> r2 (B2); LN3 -> quant -> Xp
  long n = (long)b*4096 + s0 + c;
  const float* xp = x + n*64 + g*16;
  float xa[16];
  #pragma unroll
  for (int i4 = 0; i4 < 4; i4++){
    float4 f = ((const float4*)xp)[i4];
    xa[4*i4+0]=f.x; xa[4*i4+1]=f.y; xa[4*i4+2]=f.z; xa[4*i4+3]=f.w;
  }
  float2 m2 = mr[n];
  float d[16];
  #pragma unroll
  for (int i4 = 0; i4 < 4; i4++){
    float4 f = *(const float4*)&B1[c][g*16 + 4*i4];
    d[4*i4+0]=f.x; d[4*i4+1]=f.y; d[4*i4+2]=f.z; d[4*i4+3]=f.w;
  }
  #pragma unroll
  for (int i = 0; i < 16; i++){
    float xn_i = (xa[i]-m2.x)*m2.y*ln1g[g*16+i] + ln1b[g*16+i];
    d[i] -= xn_i;
  }
  float s = 0.f;
  #pragma unroll
  for (int i = 0; i < 16; i++) s += d[i];
  s += __shfl_xor(s,1); s += __shfl_xor(s,2);
  float mean = s*(1.0f/64.0f);
  float vs = 0.f;
  #pragma unroll
  for (int i = 0; i < 16; i++){ float dd = d[i]-mean; vs += dd*dd; }
  vs += __shfl_xor(vs,1); vs += __shfl_xor(vs,2);
  float rs = rsqrtf(vs*(1.0f/64.0f) + LNE);
  float r2[16];
  #pragma unroll
  for (int i = 0; i < 16; i++){
    float t2 = (d[i]-mean)*rs*ln2g[g*16+i] + ln2b[g*16+i];
    r2[i] = t2 + xa[i];
  }
  #pragma unroll
  for (int i4 = 0; i4 < 4; i4++)
    *(float4*)&B2[c][g*16+4*i4] = make_float4(r2[4*i4],r2[4*i4+1],r2[4*i4+2],r2[4*i4+3]);
  s = 0.f;
  #pragma unroll
  for (int i = 0; i < 16; i++) s += r2[i];
  s += __shfl_xor(s,1); s += __shfl_xor(s,2);
  float mean3 = s*(1.0f/64.0f);
  vs = 0.f;
  #pragma unroll
  for (int i = 0; i < 16; i++){ float dd = r2[i]-mean3; vs += dd*dd; }
  vs += __shfl_xor(vs,1); vs += __shfl_xor(vs,2);
  float rs3 = rsqrtf(vs*(1.0f/64.0f) + LNE);
  float u16v[16]; float amax = 0.f;
  #pragma unroll
  for (int i = 0; i < 16; i++){
    float u = (r2[i]-mean3)*rs3*ln3g[g*16+i] + ln3b[g*16+i];
    u16v[i] = u; amax = fmaxf(amax, fabsf(u));
  }
  amax = fmaxf(amax, __shfl_xor(amax,1)); amax = fmaxf(amax, __shfl_xor(amax,2));
  float gamma = QBC / fmaxf(amax, EPSQ);
  #pragma unroll
  for (int i4 = 0; i4 < 4; i4++){
    float q0 = fminf(fmaxf(rintf(u16v[4*i4+0]*gamma), -128.f), 127.f);
    float q1 = fminf(fmaxf(rintf(u16v[4*i4+1]*gamma), -128.f), 127.f);
    float q2 = fminf(fmaxf(rintf(u16v[4*i4+2]*gamma), -128.f), 127.f);
    float q3 = fminf(fmaxf(rintf(u16v[4*i4+3]*gamma), -128.f), 127.f);
    Xp[c][g*4+i4] = pack4(q0,q1,q2,q3);
  }
  if (g == 0) gam1[c] = gamma;
  __syncthreads();
  // P4: FFN1 (int8)
  int ac2[4][4] = {};
  #pragma unroll
  for (int kp = 0; kp < 16; kp++){
    int av[4], bv2[4];
    #pragma unroll
    for (int i = 0; i < 4; i++) av[i] = Xp[r0+i][kp];
    #pragma unroll
    for (int j = 0; j < 4; j++) bv2[j] = Wp[0][c0+j][kp];
    #pragma unroll
    for (int i = 0; i < 4; i++)
      #pragma unroll
      for (int j = 0; j < 4; j++)
        ac2[i][j] = SDOT4(av[i], bv2[j], ac2[i][j]);
  }
  __syncthreads();
  float beta1 = beta5[3], beta2 = beta5[4];
  #pragma unroll
  for (int i = 0; i < 4; i++){
    float sc = beta1 / gam1[r0+i];
    #pragma unroll
    for (int j = 0; j < 4; j++)
      B1[r0+i][c0+j] = gelu_f((float)ac2[i][j]*sc + f1b[c0+j]);
  }
  __syncthreads();
  // P5: LN4 + quant
  float gl[16];
  #pragma unroll
  for (int i4 = 0; i4 < 4; i4++){
    float4 f = *(const float4*)&B1[c][g*16 + 4*i4];
    gl[4*i4+0]=f.x; gl[4*i4+1]=f.y; gl[4*i4+2]=f.z; gl[4*i4+3]=f.w;
  }
  s = 0.f;
  #pragma unroll
  for (int i = 0; i < 16; i++) s += gl[i];
  s += __shfl_xor(s,1); s += __shfl_xor(s,2);
  float mean4 = s*(1.0f/64.0f);
  vs = 0.f;
  #pragma unroll
  for (int i = 0; i < 16; i++){ float dd = gl[i]-mean4; vs += dd*dd; }
  vs += __shfl_xor(vs,1); vs += __shfl_xor(vs,2);
  float rs4 = rsqrtf(vs*(1.0f/64.0f) + LNE);
  amax = 0.f;
  #pragma unroll
  for (int i = 0; i < 16; i++){
    float u = (gl[i]-mean4)*rs4*ln4g[g*16+i] + ln4b[g*16+i];
    u16v[i] = u; amax = fmaxf(amax, fabsf(u));
  }
  amax = fmaxf(amax, __shfl_xor(amax,1)); amax = fmaxf(amax, __shfl_xor(amax,2));
  float gamma2 = QBC / fmaxf(amax, EPSQ);
  #pragma unroll
  for (int i4 = 0; i4 < 4; i4++){
    float q0 = fminf(fmaxf(rintf(u16v[4*i4+0]*gamma2), -128.f), 127.f);
    float q1 = fminf(fmaxf(rintf(u16v[4*i4+1]*gamma2), -128.f), 127.f);
    float q2 = fminf(fmaxf(rintf(u16v[4*i4+2]*gamma2), -128.f), 127.f);
    float q3 = fminf(fmaxf(rintf(u16v[4*i4+3]*gamma2), -128.f), 127.f);
    Xp[c][g*4+i4] = pack4(q0,q1,q2,q3);
  }
  if (g == 0) gam2[c] = gamma2;
  __syncthreads();
  // P6: FFN2 (int8) + final add
  int ac3[4][4] = {};
  #pragma unroll
  for (int kp = 0; kp < 16; kp++){
    int av[4], bv2[4];
    #pragma unroll
    for (int i = 0; i < 4; i++) av[i] = Xp[r0+i][kp];
    #pragma unroll
    for (int j = 0; j < 4; j++) bv2[j] = Wp[1][c0+j][kp];
    #pragma unroll
    for (int i = 0; i < 4; i++)
      #pragma unroll
      for (int j = 0; j < 4; j++)
        ac3[i][j] = SDOT4(av[i], bv2[j], ac3[i][j]);
  }
  float4 bf = *(const float4*)&f2b[c0];
  #pragma unroll
  for (int i = 0; i < 4; i++){
    float sc = beta2 / gam2[r0+i];
    float4 rr = *(const float4*)&B2[r0+i][c0];
    f32x4 o;
    o.x = (float)ac3[i][0]*sc + bf.x + rr.x;
    o.y = (float)ac3[i][1]*sc + bf.y + rr.y;
    o.z = (float)ac3[i][2]*sc + bf.z + rr.z;
    o.w = (float)ac3[i][3]*sc + bf.w + rr.w;
    __builtin_nontemporal_store(o, (f32x4*)&out[((long)b*4096 + s0 + r0 + i)*64 + c0]);
  }
}

extern "C" void kernel_launch(void* const* d_in, const int* in_sizes, int n_in,
                              void* d_out, int out_size, void* d_ws, size_t ws_size,
                              hipStream_t stream){
  const float* x    = (const float*)d_in[0];
  const float* it2  = (const float*)d_in[1];
  const float* qw   = (const float*)d_in[2];
  const float* qb   = (const float*)d_in[3];
  const float* kw   = (const float*)d_in[4];
  const float* kb   = (const float*)d_in[5];
  const float* vw   = (const float*)d_in[6];
  const float* vb   = (const float*)d_in[7];
  const float* f1w  = (const float*)d_in[8];
  const float* f1b  = (const float*)d_in[9];
  const float* f2w  = (const float*)d_in[10];
  const float* f2b  = (const float*)d_in[11];
  const float* c1w  = (const float*)d_in[12];
  const float* c1b  = (const float*)d_in[13];
  const float* c2w  = (const float*)d_in[14];
  const float* c2b  = (const float*)d_in[15];
  const float* c3w  = (const float*)d_in[16];
  const float* c3b  = (const float*)d_in[17];
  const float* ln1g = (const float*)d_in[18];
  const float* ln1b = (const float*)d_in[19];
  const float* ln2g = (const float*)d_in[20];
  const float* ln2b = (const float*)d_in[21];
  const float* ln3g = (const float*)d_in[22];
  const float* ln3b = (const float*)d_in[23];
  const float* ln4g = (const float*)d_in[24];
  const float* ln4b = (const float*)d_in[25];
  float* out = (float*)d_out;

  char* w = (char*)d_ws;
  int*    wpk   = (int*)(w + OFF_WPK);
  float*  beta5 = (float*)(w + OFF_BETA);
  float*  ig    = (float*)(w + OFF_IG);
  float2* mr    = (float2*)(w + OFF_MR);
  short*  q16   = (short*)(w + OFF_Q);
  short*  k16   = (short*)(w + OFF_K);
  short*  v16   = (short*)(w + OFF_V);
  float*  sco   = (float*)(w + OFF_SC);

  hipLaunchKernelGGL(k_prep, dim3(37),   dim3(1024), 0, stream,
                     qw, kw, vw, f1w, f2w, it2, c1w, c1b, c2w, c2b, c3w, c3b, wpk, beta5, sco);
  hipLaunchKernelGGL(k_qkv,  dim3(2048), dim3(256), 0, stream,
                     x, ln1g, ln1b, wpk, mr, ig, q16, k16, v16);
  hipLaunchKernelGGL(k_qk,   dim3(1024), dim3(256), 0, stream,
                     q16, k16, ig, beta5, qb, kb, sco);
  hipLaunchKernelGGL(k_epi,  dim3(2048), dim3(256), 0, stream,
                     x, v16, sco, mr, ig, beta5, wpk, ln1g, ln1b,
                     ln2g, ln2b, ln3g, ln3b, ln4g, ln4b, vb, f1b, f2b, out);
}

// Round 10
// 269.837 us; speedup vs baseline: 1.5193x; 1.1925x over previous
//
#include <hip/hip_runtime.h>

#define EPSQ 1e-8f
#define QBC  127.0f
#define LNE  1e-5f

typedef float f32x4 __attribute__((ext_vector_type(4)));

// ---- sdot4: int8x4 dot product ----
#if defined(__has_builtin)
#  if __has_builtin(__builtin_amdgcn_sdot4)
#    define SDOT4(a,b,c) __builtin_amdgcn_sdot4((a),(b),(c),false)
#  endif
#endif
#ifndef SDOT4
__device__ __forceinline__ int sdot4_sw(int a, int b, int c){
  c += ((a<<24)>>24) * ((b<<24)>>24);
  c += ((a<<16)>>24) * ((b<<16)>>24);
  c += ((a<< 8)>>24) * ((b<< 8)>>24);
  c += ( a>>24     ) * ( b>>24     );
  return c;
}
#  define SDOT4(a,b,c) sdot4_sw((a),(b),(c))
#endif

// ws byte offsets
constexpr size_t OFF_WPK  = 0;                       // 5*1024 ints (packed ternary rows)
constexpr size_t OFF_BETA = 20480;                   // 5 floats (pad)
constexpr size_t OFF_IG   = 20544;                   // 131072 floats: amax/127 per row
constexpr size_t OFF_MR   = OFF_IG + 524288;         // 131072 float2 (mean, rsqrt)
constexpr size_t OFF_Q    = OFF_MR + 1048576;        // 8388608 shorts
constexpr size_t OFF_K    = OFF_Q  + 16777216;
constexpr size_t OFF_V    = OFF_K  + 16777216;
constexpr size_t OFF_SC   = OFF_V  + 16777216;       // 131072 floats (scores -> attn)
constexpr size_t OFF_SP   = OFF_SC + 524288;         // 32*16*4096 floats (qk partials, 8.4 MB)

__device__ __forceinline__ float gelu_f(float v){
  return 0.5f * v * (1.0f + erff(v * 0.70710678118654752f));
}
__device__ __forceinline__ int pack4(float q0, float q1, float q2, float q3){
  return ((int)q0 & 255) | (((int)q1 & 255) << 8) | (((int)q2 & 255) << 16) | (((int)q3 & 255) << 24);
}

// ---------------- K1: blocks 0-4 weight quantize+pack; blocks 5-36 conv path ------------------
__global__ __launch_bounds__(1024) void k_prep(
    const float* qw, const float* kw, const float* vw, const float* f1w, const float* f2w,
    const float* it2, const float* c1w, const float* c1b, const float* c2w, const float* c2b,
    const float* c3w, const float* c3b, int* __restrict__ wpk, float* __restrict__ beta5,
    float* __restrict__ sco){
  __shared__ float smem[1024 + 2*64*65];
  int t = threadIdx.x;
  if (blockIdx.x < 5){
    int m = blockIdx.x;
    const float* w = (m==0)?qw:(m==1)?kw:(m==2)?vw:(m==3)?f1w:f2w;
    float* red = smem;
    float s = 0.f;
    for (int i = t; i < 4096; i += 1024) s += fabsf(w[i]);
    red[t] = s; __syncthreads();
    for (int o = 512; o > 0; o >>= 1){ if (t < o) red[t] += red[t+o]; __syncthreads(); }
    float beta = fmaxf(red[0] * (1.0f/4096.0f), EPSQ);
    if (t == 0) beta5[m] = beta;
    int* dst = wpk + m*1024;
    if (t < 1024){
      int row = t >> 4, kp = t & 15;
      int v = 0;
      #pragma unroll
      for (int j = 0; j < 4; j++){
        float q = rintf(w[row*64 + kp*4 + j] / beta);
        q = fminf(fmaxf(q, -1.f), 1.f);
        v |= ((int)q & 255) << (8*j);
      }
      dst[t] = v;
    }
  } else {
    int b = blockIdx.x - 5;
    float* in32 = smem;
    float (*Aa)[65] = (float(*)[65])(smem + 1024);
    float (*Bb)[65] = (float(*)[65])(smem + 1024 + 64*65);
    for (int i = t; i < 1024; i += 1024) in32[i] = it2[b*1024 + i];
    __syncthreads();
    for (int p = t; p < 4096; p += 1024){
      int i = p >> 6, j = p & 63;
      float si = 0.5f*i - 0.25f, fi = floorf(si), wi = si - fi;
      int i0 = min(max((int)fi, 0), 31), i1 = min(max((int)fi + 1, 0), 31);
      float sj = 0.5f*j - 0.25f, fj = floorf(sj), wj = sj - fj;
      int j0 = min(max((int)fj, 0), 31), j1 = min(max((int)fj + 1, 0), 31);
      float v00 = in32[i0*32+j0], v01 = in32[i0*32+j1];
      float v10 = in32[i1*32+j0], v11 = in32[i1*32+j1];
      Aa[i][j] = (1.f-wi)*((1.f-wj)*v00 + wj*v01) + wi*((1.f-wj)*v10 + wj*v11);
    }
    __syncthreads();
    {
      float w9[9]; for (int q2=0;q2<9;q2++) w9[q2]=c1w[q2]; float bb = c1b[0];
      for (int p = t; p < 4096; p += 1024){
        int i = p>>6, j = p&63; float s = bb;
        #pragma unroll
        for (int di=-1; di<=1; di++)
          #pragma unroll
          for (int dj=-1; dj<=1; dj++){
            int ii=i+di, jj=j+dj;
            if (ii>=0 && ii<64 && jj>=0 && jj<64) s += w9[(di+1)*3+dj+1]*Aa[ii][jj];
          }
        Bb[i][j] = gelu_f(s);
      }
    }
    __syncthreads();
    {
      float w9[9]; for (int q2=0;q2<9;q2++) w9[q2]=c2w[q2]; float bb = c2b[0];
      for (int p = t; p < 4096; p += 1024){
        int i = p>>6, j = p&63; float s = bb;
        #pragma unroll
        for (int di=-1; di<=1; di++)
          #pragma unroll
          for (int dj=-1; dj<=1; dj++){
            int ii=i+di, jj=j+dj;
            if (ii>=0 && ii<64 && jj>=0 && jj<64) s += w9[(di+1)*3+dj+1]*Bb[ii][jj];
          }
        Aa[i][j] = gelu_f(s);
      }
    }
    __syncthreads();
    {
      float w9[9]; for (int q2=0;q2<9;q2++) w9[q2]=c3w[q2]; float bb = c3b[0];
      for (int p = t; p < 4096; p += 1024){
        int i = p>>6, j = p&63; float s = bb;
        #pragma unroll
        for (int di=-1; di<=1; di++)
          #pragma unroll
          for (int dj=-1; dj<=1; dj++){
            int ii=i+di, jj=j+dj;
            if (ii>=0 && ii<64 && jj>=0 && jj<64) s += w9[(di+1)*3+dj+1]*Aa[ii][jj];
          }
        sco[b*4096 + p] = gelu_f(s);
      }
    }
  }
}

// ---------------- K2: LN1 + quant + QKV int8 GEMM -> int16 accums ------------------------------
__global__ __launch_bounds__(256,2) void k_qkv(const float* __restrict__ x,
    const float* __restrict__ ln1g, const float* __restrict__ ln1b,
    const int* __restrict__ wpk, float2* __restrict__ mr, float* __restrict__ ig,
    short* __restrict__ q16, short* __restrict__ k16, short* __restrict__ v16){
  __shared__ int Wp[3][64][17];
  __shared__ int Xp[64][17];
  int t = threadIdx.x;
  for (int i = t; i < 3072; i += 256){
    int m = i >> 10, rem = i & 1023;
    Wp[m][rem>>4][rem&15] = wpk[i];
  }
  int c = t >> 2, g = t & 3;
  long n = (long)blockIdx.x * 64 + c;
  const float* xr = x + n*64 + g*16;
  float xv[16];
  #pragma unroll
  for (int i4 = 0; i4 < 4; i4++){
    float4 f = ((const float4*)xr)[i4];
    xv[4*i4+0]=f.x; xv[4*i4+1]=f.y; xv[4*i4+2]=f.z; xv[4*i4+3]=f.w;
  }
  float s = 0.f;
  #pragma unroll
  for (int i = 0; i < 16; i++) s += xv[i];
  s += __shfl_xor(s,1); s += __shfl_xor(s,2);
  float mean = s * (1.0f/64.0f);
  float vs = 0.f;
  #pragma unroll
  for (int i = 0; i < 16; i++){ float dd = xv[i]-mean; vs += dd*dd; }
  vs += __shfl_xor(vs,1); vs += __shfl_xor(vs,2);
  float rs = rsqrtf(vs*(1.0f/64.0f) + LNE);
  float xnv[16]; float amax = 0.f;
  #pragma unroll
  for (int i = 0; i < 16; i++){
    float u = (xv[i]-mean)*rs*ln1g[g*16+i] + ln1b[g*16+i];
    xnv[i] = u; amax = fmaxf(amax, fabsf(u));
  }
  amax = fmaxf(amax, __shfl_xor(amax,1)); amax = fmaxf(amax, __shfl_xor(amax,2));
  float am = fmaxf(amax, EPSQ);
  float gamma = QBC / am;
  if (g == 0){ ig[n] = am * (1.0f/QBC); mr[n] = make_float2(mean, rs); }
  #pragma unroll
  for (int i4 = 0; i4 < 4; i4++){
    float q0 = fminf(fmaxf(rintf(xnv[4*i4+0]*gamma), -128.f), 127.f);
    float q1 = fminf(fmaxf(rintf(xnv[4*i4+1]*gamma), -128.f), 127.f);
    float q2 = fminf(fmaxf(rintf(xnv[4*i4+2]*gamma), -128.f), 127.f);
    float q3 = fminf(fmaxf(rintf(xnv[4*i4+3]*gamma), -128.f), 127.f);
    Xp[c][g*4+i4] = pack4(q0,q1,q2,q3);
  }
  __syncthreads();

  int r0 = (t >> 4) << 2, c0 = (t & 15) << 2;
  #pragma unroll
  for (int m = 0; m < 3; m++){
    int acc[4][4] = {};
    #pragma unroll
    for (int kp = 0; kp < 16; kp++){
      int av[4], bv[4];
      #pragma unroll
      for (int i = 0; i < 4; i++) av[i] = Xp[r0+i][kp];
      #pragma unroll
      for (int j = 0; j < 4; j++) bv[j] = Wp[m][c0+j][kp];
      #pragma unroll
      for (int i = 0; i < 4; i++)
        #pragma unroll
        for (int j = 0; j < 4; j++)
          acc[i][j] = SDOT4(av[i], bv[j], acc[i][j]);
    }
    short* op = ((m==0)?q16:(m==1)?k16:v16) + (long)blockIdx.x*4096;
    #pragma unroll
    for (int i = 0; i < 4; i++){
      short4 s4;
      s4.x = (short)acc[i][0]; s4.y = (short)acc[i][1];
      s4.z = (short)acc[i][2]; s4.w = (short)acc[i][3];
      *(short4*)&op[(r0+i)*64 + c0] = s4;
    }
  }
}

// ---------------- K3: per-chunk QK^T partials (NO atomics); 16 chunks per batch ----------------
__global__ __launch_bounds__(256,2) void k_qk(
    const short* __restrict__ q16, const short* __restrict__ k16,
    const float* __restrict__ ig, const float* __restrict__ beta5,
    const float* __restrict__ qbias, const float* __restrict__ kbias,
    float* __restrict__ sp){
  __shared__ float Qs[64][68];
  __shared__ float Kt[64][68];
  __shared__ float qbs[64], kbs[64];
  int t = threadIdx.x;
  int b = blockIdx.x >> 4, ch = blockIdx.x & 15;
  int c = t >> 2, g = t & 3;
  int r0 = (t >> 4) << 2, c0 = (t & 15) << 2;
  if (t < 64){ qbs[t] = qbias[t]; kbs[t] = kbias[t]; }
  float bq = beta5[0], bk = beta5[1];
  const short* qbase = q16 + (long)b*262144 + (long)c*4096;
  const short* kbase = k16 + (long)b*262144 + (long)c*4096;
  float acc[4][4] = {};
  for (int sub = 0; sub < 4; sub++){
    int t0 = ch*256 + sub*64 + g*16;
    int4 qa = *(const int4*)(qbase + t0);
    int4 qb2 = *(const int4*)(qbase + t0 + 8);
    int4 ka = *(const int4*)(kbase + t0);
    int4 kb2 = *(const int4*)(kbase + t0 + 8);
    float sgi = ig[b*4096 + c*64 + ch*4 + sub];
    float sq = bq * sgi, sk = bk * sgi;
    __syncthreads();
    int qi[8] = {qa.x,qa.y,qa.z,qa.w,qb2.x,qb2.y,qb2.z,qb2.w};
    int ki[8] = {ka.x,ka.y,ka.z,ka.w,kb2.x,kb2.y,kb2.z,kb2.w};
    #pragma unroll
    for (int w2 = 0; w2 < 8; w2++){
      int e0 = g*16 + 2*w2, e1 = e0 + 1;
      Qs[c][e0] = (float)((qi[w2]<<16)>>16)*sq + qbs[e0];
      Qs[c][e1] = (float)( qi[w2]>>16      )*sq + qbs[e1];
      Kt[e0][c] = (float)((ki[w2]<<16)>>16)*sk + kbs[e0];
      Kt[e1][c] = (float)( ki[w2]>>16      )*sk + kbs[e1];
    }
    __syncthreads();
    for (int k4 = 0; k4 < 64; k4 += 4){
      float4 a[4], bv[4];
      #pragma unroll
      for (int i = 0; i < 4; i++) a[i] = *(const float4*)&Qs[r0+i][k4];
      #pragma unroll
      for (int kk = 0; kk < 4; kk++) bv[kk] = *(const float4*)&Kt[k4+kk][c0];
      #pragma unroll
      for (int i = 0; i < 4; i++){
        const float* ap = (const float*)&a[i];
        #pragma unroll
        for (int kk = 0; kk < 4; kk++){
          float av = ap[kk];
          acc[i][0] = fmaf(av, bv[kk].x, acc[i][0]);
          acc[i][1] = fmaf(av, bv[kk].y, acc[i][1]);
          acc[i][2] = fmaf(av, bv[kk].z, acc[i][2]);
          acc[i][3] = fmaf(av, bv[kk].w, acc[i][3]);
        }
      }
    }
  }
  float* spo = sp + ((long)b*16 + ch)*4096;
  #pragma unroll
  for (int i = 0; i < 4; i++){
    f32x4 o; o.x = acc[i][0]*0.125f; o.y = acc[i][1]*0.125f;
    o.z = acc[i][2]*0.125f; o.w = acc[i][3]*0.125f;
    *(f32x4*)&spo[(r0+i)*64 + c0] = o;
  }
}

// ---------------- K4: reduce partials + softmax -> attn in sco ---------------------------------
__global__ __launch_bounds__(256) void k_rsm(const float* __restrict__ sp, float* __restrict__ sco){
  int row = blockIdx.x*4 + (threadIdx.x >> 6);   // 0..2047 = b*64 + e
  int lane = threadIdx.x & 63;                   // f
  int b = row >> 6, e = row & 63;
  long off = (long)b*4096 + e*64 + lane;
  float v = sco[off];                            // conv "it" init
  const float* spp = sp + (long)b*65536 + e*64 + lane;
  #pragma unroll
  for (int ch = 0; ch < 16; ch++) v += spp[ch*4096];
  float mx = v;
  #pragma unroll
  for (int o = 1; o < 64; o <<= 1) mx = fmaxf(mx, __shfl_xor(mx, o));
  float ev = expf(v - mx);
  float sum = ev;
  #pragma unroll
  for (int o = 1; o < 64; o <<= 1) sum += __shfl_xor(sum, o);
  sco[off] = ev / sum;
}

// ---------------- K5: PV + LN2 + res + LN3 + FFN1 + LN4 + FFN2 (attn precomputed) -------------
__global__ __launch_bounds__(256,4) void k_epi(const float* __restrict__ x,
    const short* __restrict__ v16, const float* __restrict__ sco,
    const float2* __restrict__ mr, const float* __restrict__ ig,
    const float* __restrict__ beta5, const int* __restrict__ wpk,
    const float* ln1g, const float* ln1b,
    const float* ln2g, const float* ln2b, const float* ln3g, const float* ln3b,
    const float* ln4g, const float* ln4b, const float* __restrict__ vbias,
    const float* f1b, const float* f2b, float* __restrict__ out){
  __shared__ float B1[64][68];
  __shared__ float B2[64][68];
  __shared__ int Xp[64][17];
  __shared__ float gam1[64], gam2[64];
  int t = threadIdx.x;
  int b = blockIdx.x >> 6;
  int s0 = (blockIdx.x & 63) << 6;
  float bv_ = beta5[2];
  for (int i = t; i < 4096; i += 256){
    int r = i >> 6, cc = i & 63;
    B1[r][cc] = sco[b*4096 + i];                                        // attn (final)
    float sv = bv_ * ig[b*4096 + r*64 + (s0 >> 6)];
    B2[r][cc] = (float)v16[(long)b*262144 + (long)r*4096 + s0 + cc] * sv + vbias[cc];
  }
  __syncthreads();
  int c = t >> 2, g = t & 3;
  int r0 = (t >> 4) << 2, c0 = (t & 15) << 2;
  // P1: Ov = attn @ Vt
  float acc[4][4] = {};
  for (int k4 = 0; k4 < 64; k4 += 4){
    float4 a[4], bv[4];
    #pragma unroll
    for (int i = 0; i < 4; i++) a[i] = *(const float4*)&B1[r0+i][k4];
    #pragma unroll
    for (int kk = 0; kk < 4; kk++) bv[kk] = *(const float4*)&B2[k4+kk][c0];
    #pragma unroll
    for (int i = 0; i < 4; i++){
      const float* ap = (const float*)&a[i];
      #pragma unroll
      for (int kk = 0; kk < 4; kk++){
        float av = ap[kk];
        acc[i][0] = fmaf(av, bv[kk].x, acc[i][0]);
        acc[i][1] = fmaf(av, bv[kk].y, acc[i][1]);
        acc[i][2] = fmaf(av, bv[kk].z, acc[i][2]);
        acc[i][3] = fmaf(av, bv[kk].w, acc[i][3]);
      }
    }
  }
  __syncthreads();
  #pragma unroll
  for (int i = 0; i < 4; i++)
    #pragma unroll
    for (int j = 0; j < 4; j++) B1[c0+j][r0+i] = acc[i][j];   // Ov^T
  __syncthreads();
  // P3: recompute xn; d = attnout - xn; LN2; +x -> r2 (B2); LN3 -> quant -> Xp
  long n = (long)b*4096 + s0 + c;
  const float* xp = x + n*64 + g*16;
  float xa[16];
  #pragma unroll
  for (int i4 = 0; i4 < 4; i4++){
    float4 f = ((const float4*)xp)[i4];
    xa[4*i4+0]=f.x; xa[4*i4+1]=f.y; xa[4*i4+2]=f.z; xa[4*i4+3]=f.w;
  }
  float2 m2 = mr[n];
  float d[16];
  #pragma unroll
  for (int i4 = 0; i4 < 4; i4++){
    float4 f = *(const float4*)&B1[c][g*16 + 4*i4];
    d[4*i4+0]=f.x; d[4*i4+1]=f.y; d[4*i4+2]=f.z; d[4*i4+3]=f.w;
  }
  #pragma unroll
  for (int i = 0; i < 16; i++){
    float xn_i = (xa[i]-m2.x)*m2.y*ln1g[g*16+i] + ln1b[g*16+i];
    d[i] -= xn_i;
  }
  float s = 0.f;
  #pragma unroll
  for (int i = 0; i < 16; i++) s += d[i];
  s += __shfl_xor(s,1); s += __shfl_xor(s,2);
  float mean = s*(1.0f/64.0f);
  float vs = 0.f;
  #pragma unroll
  for (int i = 0; i < 16; i++){ float dd = d[i]-mean; vs += dd*dd; }
  vs += __shfl_xor(vs,1); vs += __shfl_xor(vs,2);
  float rs = rsqrtf(vs*(1.0f/64.0f) + LNE);
  float r2[16];
  #pragma unroll
  for (int i = 0; i < 16; i++){
    float t2 = (d[i]-mean)*rs*ln2g[g*16+i] + ln2b[g*16+i];
    r2[i] = t2 + xa[i];
  }
  #pragma unroll
  for (int i4 = 0; i4 < 4; i4++)
    *(float4*)&B2[c][g*16+4*i4] = make_float4(r2[4*i4],r2[4*i4+1],r2[4*i4+2],r2[4*i4+3]);
  s = 0.f;
  #pragma unroll
  for (int i = 0; i < 16; i++) s += r2[i];
  s += __shfl_xor(s,1); s += __shfl_xor(s,2);
  float mean3 = s*(1.0f/64.0f);
  vs = 0.f;
  #pragma unroll
  for (int i = 0; i < 16; i++){ float dd = r2[i]-mean3; vs += dd*dd; }
  vs += __shfl_xor(vs,1); vs += __shfl_xor(vs,2);
  float rs3 = rsqrtf(vs*(1.0f/64.0f) + LNE);
  float u16v[16]; float amax = 0.f;
  #pragma unroll
  for (int i = 0; i < 16; i++){
    float u = (r2[i]-mean3)*rs3*ln3g[g*16+i] + ln3b[g*16+i];
    u16v[i] = u; amax = fmaxf(amax, fabsf(u));
  }
  amax = fmaxf(amax, __shfl_xor(amax,1)); amax = fmaxf(amax, __shfl_xor(amax,2));
  float gamma = QBC / fmaxf(amax, EPSQ);
  #pragma unroll
  for (int i4 = 0; i4 < 4; i4++){
    float q0 = fminf(fmaxf(rintf(u16v[4*i4+0]*gamma), -128.f), 127.f);
    float q1 = fminf(fmaxf(rintf(u16v[4*i4+1]*gamma), -128.f), 127.f);
    float q2 = fminf(fmaxf(rintf(u16v[4*i4+2]*gamma), -128.f), 127.f);
    float q3 = fminf(fmaxf(rintf(u16v[4*i4+3]*gamma), -128.f), 127.f);
    Xp[c][g*4+i4] = pack4(q0,q1,q2,q3);
  }
  if (g == 0) gam1[c] = gamma;
  __syncthreads();
  // P4: FFN1 (int8), weights direct from global (L1/L2-hot)
  const int* w1 = wpk + 3*1024;
  int ac2[4][4] = {};
  #pragma unroll
  for (int kp = 0; kp < 16; kp++){
    int av[4], bv2[4];
    #pragma unroll
    for (int i = 0; i < 4; i++) av[i] = Xp[r0+i][kp];
    #pragma unroll
    for (int j = 0; j < 4; j++) bv2[j] = w1[(c0+j)*16 + kp];
    #pragma unroll
    for (int i = 0; i < 4; i++)
      #pragma unroll
      for (int j = 0; j < 4; j++)
        ac2[i][j] = SDOT4(av[i], bv2[j], ac2[i][j]);
  }
  __syncthreads();
  float beta1 = beta5[3], beta2 = beta5[4];
  #pragma unroll
  for (int i = 0; i < 4; i++){
    float sc = beta1 / gam1[r0+i];
    #pragma unroll
    for (int j = 0; j < 4; j++)
      B1[r0+i][c0+j] = gelu_f((float)ac2[i][j]*sc + f1b[c0+j]);
  }
  __syncthreads();
  // P5: LN4 + quant
  float gl[16];
  #pragma unroll
  for (int i4 = 0; i4 < 4; i4++){
    float4 f = *(const float4*)&B1[c][g*16 + 4*i4];
    gl[4*i4+0]=f.x; gl[4*i4+1]=f.y; gl[4*i4+2]=f.z; gl[4*i4+3]=f.w;
  }
  s = 0.f;
  #pragma unroll
  for (int i = 0; i < 16; i++) s += gl[i];
  s += __shfl_xor(s,1); s += __shfl_xor(s,2);
  float mean4 = s*(1.0f/64.0f);
  vs = 0.f;
  #pragma unroll
  for (int i = 0; i < 16; i++){ float dd = gl[i]-mean4; vs += dd*dd; }
  vs += __shfl_xor(vs,1); vs += __shfl_xor(vs,2);
  float rs4 = rsqrtf(vs*(1.0f/64.0f) + LNE);
  amax = 0.f;
  #pragma unroll
  for (int i = 0; i < 16; i++){
    float u = (gl[i]-mean4)*rs4*ln4g[g*16+i] + ln4b[g*16+i];
    u16v[i] = u; amax = fmaxf(amax, fabsf(u));
  }
  amax = fmaxf(amax, __shfl_xor(amax,1)); amax = fmaxf(amax, __shfl_xor(amax,2));
  float gamma2 = QBC / fmaxf(amax, EPSQ);
  #pragma unroll
  for (int i4 = 0; i4 < 4; i4++){
    float q0 = fminf(fmaxf(rintf(u16v[4*i4+0]*gamma2), -128.f), 127.f);
    float q1 = fminf(fmaxf(rintf(u16v[4*i4+1]*gamma2), -128.f), 127.f);
    float q2 = fminf(fmaxf(rintf(u16v[4*i4+2]*gamma2), -128.f), 127.f);
    float q3 = fminf(fmaxf(rintf(u16v[4*i4+3]*gamma2), -128.f), 127.f);
    Xp[c][g*4+i4] = pack4(q0,q1,q2,q3);
  }
  if (g == 0) gam2[c] = gamma2;
  __syncthreads();
  // P6: FFN2 (int8) + final add
  const int* w2 = wpk + 4*1024;
  int ac3[4][4] = {};
  #pragma unroll
  for (int kp = 0; kp < 16; kp++){
    int av[4], bv2[4];
    #pragma unroll
    for (int i = 0; i < 4; i++) av[i] = Xp[r0+i][kp];
    #pragma unroll
    for (int j = 0; j < 4; j++) bv2[j] = w2[(c0+j)*16 + kp];
    #pragma unroll
    for (int i = 0; i < 4; i++)
      #pragma unroll
      for (int j = 0; j < 4; j++)
        ac3[i][j] = SDOT4(av[i], bv2[j], ac3[i][j]);
  }
  float4 bf = *(const float4*)&f2b[c0];
  #pragma unroll
  for (int i = 0; i < 4; i++){
    float sc = beta2 / gam2[r0+i];
    float4 rr = *(const float4*)&B2[r0+i][c0];
    f32x4 o;
    o.x = (float)ac3[i][0]*sc + bf.x + rr.x;
    o.y = (float)ac3[i][1]*sc + bf.y + rr.y;
    o.z = (float)ac3[i][2]*sc + bf.z + rr.z;
    o.w = (float)ac3[i][3]*sc + bf.w + rr.w;
    __builtin_nontemporal_store(o, (f32x4*)&out[((long)b*4096 + s0 + r0 + i)*64 + c0]);
  }
}

extern "C" void kernel_launch(void* const* d_in, const int* in_sizes, int n_in,
                              void* d_out, int out_size, void* d_ws, size_t ws_size,
                              hipStream_t stream){
  const float* x    = (const float*)d_in[0];
  const float* it2  = (const float*)d_in[1];
  const float* qw   = (const float*)d_in[2];
  const float* qb   = (const float*)d_in[3];
  const float* kw   = (const float*)d_in[4];
  const float* kb   = (const float*)d_in[5];
  const float* vw   = (const float*)d_in[6];
  const float* vb   = (const float*)d_in[7];
  const float* f1w  = (const float*)d_in[8];
  const float* f1b  = (const float*)d_in[9];
  const float* f2w  = (const float*)d_in[10];
  const float* f2b  = (const float*)d_in[11];
  const float* c1w  = (const float*)d_in[12];
  const float* c1b  = (const float*)d_in[13];
  const float* c2w  = (const float*)d_in[14];
  const float* c2b  = (const float*)d_in[15];
  const float* c3w  = (const float*)d_in[16];
  const float* c3b  = (const float*)d_in[17];
  const float* ln1g = (const float*)d_in[18];
  const float* ln1b = (const float*)d_in[19];
  const float* ln2g = (const float*)d_in[20];
  const float* ln2b = (const float*)d_in[21];
  const float* ln3g = (const float*)d_in[22];
  const float* ln3b = (const float*)d_in[23];
  const float* ln4g = (const float*)d_in[24];
  const float* ln4b = (const float*)d_in[25];
  float* out = (float*)d_out;

  char* w = (char*)d_ws;
  int*    wpk   = (int*)(w + OFF_WPK);
  float*  beta5 = (float*)(w + OFF_BETA);
  float*  ig    = (float*)(w + OFF_IG);
  float2* mr    = (float2*)(w + OFF_MR);
  short*  q16   = (short*)(w + OFF_Q);
  short*  k16   = (short*)(w + OFF_K);
  short*  v16   = (short*)(w + OFF_V);
  float*  sco   = (float*)(w + OFF_SC);
  float*  sp    = (float*)(w + OFF_SP);

  hipLaunchKernelGGL(k_prep, dim3(37),   dim3(1024), 0, stream,
                     qw, kw, vw, f1w, f2w, it2, c1w, c1b, c2w, c2b, c3w, c3b, wpk, beta5, sco);
  hipLaunchKernelGGL(k_qkv,  dim3(2048), dim3(256), 0, stream,
                     x, ln1g, ln1b, wpk, mr, ig, q16, k16, v16);
  hipLaunchKernelGGL(k_qk,   dim3(512),  dim3(256), 0, stream,
                     q16, k16, ig, beta5, qb, kb, sp);
  hipLaunchKernelGGL(k_rsm,  dim3(512),  dim3(256), 0, stream, sp, sco);
  hipLaunchKernelGGL(k_epi,  dim3(2048), dim3(256), 0, stream,
                     x, v16, sco, mr, ig, beta5, wpk, ln1g, ln1b,
                     ln2g, ln2b, ln3g, ln3b, ln4g, ln4b, vb, f1b, f2b, out);
}